// Round 6
// baseline (201.563 us; speedup 1.0000x reference)
//
#include <hip/hip_runtime.h>
#include <hip/hip_bf16.h>
#include <math.h>

// Problem constants
#define NB 16
#define CH 512
#define HW 1024          // 32*32
#define INV_EPS 20.0f
#define EPS 0.05f

typedef unsigned short ushort;
typedef _Float16 half8 __attribute__((ext_vector_type(8)));
typedef _Float16 half4 __attribute__((ext_vector_type(4)));
typedef float f32x4 __attribute__((ext_vector_type(4)));

static __device__ __forceinline__ void gload16(const void* g, void* l) {
    __builtin_amdgcn_global_load_lds(
        (const __attribute__((address_space(1))) unsigned int*)g,
        (__attribute__((address_space(3))) unsigned int*)l, 16, 0, 0);
}

// ---------------------------------------------------------------------------
// K1: per-(n,c) means of pred and target over HW
__global__ __launch_bounds__(256) void k_means(const float* __restrict__ pred,
                                               const float* __restrict__ targ,
                                               float* __restrict__ pmu,
                                               float* __restrict__ tmu) {
    int bid = blockIdx.x;              // n*CH + c
    int t = threadIdx.x;
    float4 a  = ((const float4*)(pred + (size_t)bid * HW))[t];
    float4 b4 = ((const float4*)(targ + (size_t)bid * HW))[t];
    float sp = a.x + a.y + a.z + a.w;
    float st = b4.x + b4.y + b4.z + b4.w;
    __shared__ float l1[4], l2[4];
    int lane = t & 63, w = t >> 6;
    for (int o = 32; o; o >>= 1) { sp += __shfl_xor(sp, o, 64); st += __shfl_xor(st, o, 64); }
    if (lane == 0) { l1[w] = sp; l2[w] = st; }
    __syncthreads();
    if (t == 0) {
        pmu[bid] = (l1[0] + l1[1] + l1[2] + l1[3]) * (1.0f / HW);
        tmu[bid] = (l2[0] + l2[1] + l2[2] + l2[3]) * (1.0f / HW);
    }
}

// K2: ymu[c] = mean over n of tmu[n][c]
__global__ void k_ymu(const float* __restrict__ tmu, float* __restrict__ ymu) {
    int c = threadIdx.x;   // 512 threads
    float s = 0.f;
    for (int n = 0; n < NB; n++) s += tmu[n * CH + c];
    ymu[c] = s * (1.0f / NB);
}

// K3: strip-partial weight dots + centered sq-norms.
// grid (4 p-chunks, 4 c-strips, NB). Raw partials (relu applied later on totals).
__global__ __launch_bounds__(256) void k_wn4(const float* __restrict__ pred,
                                             const float* __restrict__ targ,
                                             const float* __restrict__ pmu,
                                             const float* __restrict__ tmu,
                                             const float* __restrict__ ymu,
                                             float* __restrict__ pap,
                                             float* __restrict__ pat,
                                             float* __restrict__ pnx,
                                             float* __restrict__ pny) {
    int n = blockIdx.z;
    int p = blockIdx.x * 256 + threadIdx.x;
    int c0 = blockIdx.y * 128;
    __shared__ float tm[128], pm[128], mu[128];
    if (threadIdx.x < 128) {
        tm[threadIdx.x] = tmu[n * CH + c0 + threadIdx.x];
        pm[threadIdx.x] = pmu[n * CH + c0 + threadIdx.x];
        mu[threadIdx.x] = ymu[c0 + threadIdx.x];
    }
    __syncthreads();
    const float* Pb = pred + ((size_t)n * CH + c0) * HW + p;
    const float* Tb = targ + ((size_t)n * CH + c0) * HW + p;
    float ap = 0.f, at = 0.f, nx = 0.f, ny = 0.f;
    for (int c = 0; c < 128; c++) {
        float xp = Pb[(size_t)c * HW];
        float xt = Tb[(size_t)c * HW];
        ap = fmaf(xp, tm[c], ap);
        at = fmaf(xt, pm[c], at);
        float dx = xp - mu[c]; nx = fmaf(dx, dx, nx);
        float dy = xt - mu[c]; ny = fmaf(dy, dy, ny);
    }
    size_t o = ((size_t)(blockIdx.y * NB + n)) * HW + p;
    pap[o] = ap; pat[o] = at; pnx[o] = nx; pny[o] = ny;
}

// K4: combine partials -> normalized marginals a,b + inverse norms
__global__ __launch_bounds__(256) void k_prep(const float* __restrict__ pap,
                                              const float* __restrict__ pat,
                                              const float* __restrict__ pnx,
                                              const float* __restrict__ pny,
                                              float* __restrict__ a,
                                              float* __restrict__ b,
                                              float* __restrict__ innx,
                                              float* __restrict__ inny) {
    int n = blockIdx.x, t = threadIdx.x;
    float4 ap = {0,0,0,0}, at = {0,0,0,0}, nx = {0,0,0,0}, ny = {0,0,0,0};
    for (int cs = 0; cs < 4; cs++) {
        size_t o = (size_t)(cs * NB + n) * (HW / 4) + t;
        float4 x;
        x = ((const float4*)pap)[o]; ap.x += x.x; ap.y += x.y; ap.z += x.z; ap.w += x.w;
        x = ((const float4*)pat)[o]; at.x += x.x; at.y += x.y; at.z += x.z; at.w += x.w;
        x = ((const float4*)pnx)[o]; nx.x += x.x; nx.y += x.y; nx.z += x.z; nx.w += x.w;
        x = ((const float4*)pny)[o]; ny.x += x.x; ny.y += x.y; ny.z += x.z; ny.w += x.w;
    }
    float4 wp, wt;
    wp.x = fmaxf(ap.x, 0.f) + 1e-4f + 1e-5f; wp.y = fmaxf(ap.y, 0.f) + 1e-4f + 1e-5f;
    wp.z = fmaxf(ap.z, 0.f) + 1e-4f + 1e-5f; wp.w = fmaxf(ap.w, 0.f) + 1e-4f + 1e-5f;
    wt.x = fmaxf(at.x, 0.f) + 1e-4f + 1e-5f; wt.y = fmaxf(at.y, 0.f) + 1e-4f + 1e-5f;
    wt.z = fmaxf(at.z, 0.f) + 1e-4f + 1e-5f; wt.w = fmaxf(at.w, 0.f) + 1e-4f + 1e-5f;
    float sp = wp.x + wp.y + wp.z + wp.w;
    float st = wt.x + wt.y + wt.z + wt.w;
    __shared__ float r1[4], r2[4];
    int lane = t & 63, w = t >> 6;
    for (int o = 32; o; o >>= 1) { sp += __shfl_xor(sp, o, 64); st += __shfl_xor(st, o, 64); }
    if (lane == 0) { r1[w] = sp; r2[w] = st; }
    __syncthreads();
    float scp = (float)HW / (r1[0] + r1[1] + r1[2] + r1[3]);
    float sct = (float)HW / (r2[0] + r2[1] + r2[2] + r2[3]);
    ((float4*)(a + (size_t)n * HW))[t] = make_float4(wp.x * scp, wp.y * scp, wp.z * scp, wp.w * scp);
    ((float4*)(b + (size_t)n * HW))[t] = make_float4(wt.x * sct, wt.y * sct, wt.z * sct, wt.w * sct);
    float4 ix, iy;
    ix.x = 1.f / fmaxf(sqrtf(nx.x), 1e-12f); ix.y = 1.f / fmaxf(sqrtf(nx.y), 1e-12f);
    ix.z = 1.f / fmaxf(sqrtf(nx.z), 1e-12f); ix.w = 1.f / fmaxf(sqrtf(nx.w), 1e-12f);
    iy.x = 1.f / fmaxf(sqrtf(ny.x), 1e-12f); iy.y = 1.f / fmaxf(sqrtf(ny.y), 1e-12f);
    iy.z = 1.f / fmaxf(sqrtf(ny.z), 1e-12f); iy.w = 1.f / fmaxf(sqrtf(ny.w), 1e-12f);
    ((float4*)(innx + (size_t)n * HW))[t] = ix;
    ((float4*)(inny + (size_t)n * HW))[t] = iy;
}

// K5: transpose + center + normalize -> fp16 XT[p][c], YT[p][c]
__global__ __launch_bounds__(256) void k_maketr(const float* __restrict__ pred,
                                                const float* __restrict__ targ,
                                                const float* __restrict__ ymu,
                                                const float* __restrict__ innx,
                                                const float* __restrict__ inny,
                                                _Float16* __restrict__ XT,
                                                _Float16* __restrict__ YT) {
    int z = blockIdx.z;
    int n = z >> 1, side = z & 1;
    int p0 = blockIdx.x * 64, c0 = blockIdx.y * 64;
    const float* src = side ? targ : pred;
    const float* inn = side ? inny : innx;
    _Float16* O = side ? YT : XT;
    __shared__ float til[64][65];
    int t = threadIdx.x;
    int cr = t >> 6, pc = t & 63;
#pragma unroll
    for (int r = 0; r < 16; r++) {
        int c = r * 4 + cr;
        til[c][pc] = src[((size_t)n * CH + c0 + c) * HW + p0 + pc];
    }
    __syncthreads();
    int pl = t >> 2, cg = t & 3;
    float is = inn[n * HW + p0 + pl];
    half8 hv0, hv1;
#pragma unroll
    for (int cc = 0; cc < 16; cc++) {
        int c = cg * 16 + cc;
        float val = (til[c][pl] - ymu[c0 + c]) * is;
        if (cc < 8) hv0[cc] = (_Float16)val;
        else        hv1[cc - 8] = (_Float16)val;
    }
    size_t off = ((size_t)n * HW + p0 + pl) * CH + c0 + cg * 16;
    *(half8*)(O + off) = hv0;
    *(half8*)(O + off + 8) = hv1;
}

// K6: fp16 MFMA GEMM: S[n][p][q] = sum_c XT[p][c]*YT[q][c], output fp16.
__global__ __launch_bounds__(256) void k_gemm_mfma(const _Float16* __restrict__ XT,
                                                   const _Float16* __restrict__ YT,
                                                   _Float16* __restrict__ S) {
    __shared__ char lds[32768];        // 2 bufs x 2 tiles x 8 KB
    int n = blockIdx.z;
    int p0 = blockIdx.y * 128, q0 = blockIdx.x * 128;
    int t = threadIdx.x, lane = t & 63, wid = t >> 6;
    int wr = wid >> 1, wc = wid & 1;

    const _Float16* bases[2] = {
        XT + (size_t)(n * HW + p0) * CH,
        YT + (size_t)(n * HW + q0) * CH };
    const _Float16* gsrc[4];
    int ldso[4];
#pragma unroll
    for (int r = 0; r < 4; r++) {
        int tile = r >> 1;
        int ci = (r & 1) * 256 + t;        // 16B-chunk index within tile (0..511)
        int row = ci >> 2, sp = ci & 3;    // 4 slots of 16B per 64B row
        int sl = sp ^ ((row >> 1) & 3);    // inverse swizzle on source
        gsrc[r] = bases[tile] + (size_t)row * CH + sl * 8;
        ldso[r] = tile * 8192 + ci * 16;   // linear LDS dest
    }

    int qq = lane >> 4, rA = lane & 15;
    int aoff[4], boff[4];
#pragma unroll
    for (int i = 0; i < 4; i++) {
        int ar = wr * 64 + i * 16 + rA;
        aoff[i] = ar * 64 + ((qq ^ ((ar >> 1) & 3)) * 16);
        int br = wc * 64 + i * 16 + rA;
        boff[i] = br * 64 + ((qq ^ ((br >> 1) & 3)) * 16);
    }

    f32x4 acc[4][4] = {};

#pragma unroll
    for (int r = 0; r < 4; r++) gload16(gsrc[r], &lds[ldso[r]]);
    __syncthreads();

    int cur = 0;
    for (int ks = 0; ks < 16; ks++) {
        if (ks < 15) {
            char* dst = &lds[(cur ^ 1) * 16384];
#pragma unroll
            for (int r = 0; r < 4; r++)
                gload16(gsrc[r] + (ks + 1) * 32, dst + ldso[r]);
        }
        const char* bufb = &lds[cur * 16384];
        half8 av[4], bv[4];
#pragma unroll
        for (int i = 0; i < 4; i++) {
            av[i] = *(const half8*)(bufb + aoff[i]);
            bv[i] = *(const half8*)(bufb + 8192 + boff[i]);
        }
#pragma unroll
        for (int i = 0; i < 4; i++)
#pragma unroll
            for (int j = 0; j < 4; j++)
                acc[i][j] = __builtin_amdgcn_mfma_f32_16x16x32_f16(av[i], bv[j], acc[i][j], 0, 0, 0);
        __syncthreads();
        cur ^= 1;
    }

    int rbase = p0 + wr * 64 + ((lane >> 4) << 2);
    int cbase = q0 + wc * 64 + (lane & 15);
    _Float16* Sn = S + (size_t)n * HW * HW;
#pragma unroll
    for (int i = 0; i < 4; i++)
#pragma unroll
        for (int r = 0; r < 4; r++) {
            _Float16* rowp = Sn + (size_t)(rbase + i * 16 + r) * HW + cbase;
#pragma unroll
            for (int j = 0; j < 4; j++) rowp[j * 16] = (_Float16)acc[i][j][r];
        }
}

// K7: row softmax + P emit + first Sinkhorn row half-step.
// s = row-softmax of exp((1-d/dmin)*2); P = expm1(s/eps) (fp16);
// u1_p = a_p / (1024 + rowsum(P))   [v0 = 1]
__global__ __launch_bounds__(256) void k_rowsm(const _Float16* __restrict__ S,
                                               const float* __restrict__ a,
                                               _Float16* __restrict__ P,
                                               float* __restrict__ u) {
    size_t row = blockIdx.x;           // n*HW + p
    const _Float16* Sr = S + row * HW;
    _Float16* Pr = P + row * HW;
    int t = threadIdx.x;
    half4 c4 = ((const half4*)Sr)[t];
    float d0 = 1.f - (float)c4[0], d1 = 1.f - (float)c4[1];
    float d2 = 1.f - (float)c4[2], d3 = 1.f - (float)c4[3];
    float mn = fminf(fminf(d0, d1), fminf(d2, d3));
    __shared__ float red[4];
    int lane = t & 63, w = t >> 6;
    for (int o = 32; o; o >>= 1) mn = fminf(mn, __shfl_xor(mn, o, 64));
    if (lane == 0) red[w] = mn;
    __syncthreads();
    float m = fminf(fminf(red[0], red[1]), fminf(red[2], red[3])) + 1e-5f;
    float e0 = expf((1.f - d0 / m) * 2.f);
    float e1 = expf((1.f - d1 / m) * 2.f);
    float e2 = expf((1.f - d2 / m) * 2.f);
    float e3 = expf((1.f - d3 / m) * 2.f);
    float s = e0 + e1 + e2 + e3;
    __syncthreads();
    for (int o = 32; o; o >>= 1) s += __shfl_xor(s, o, 64);
    if (lane == 0) red[w] = s;
    __syncthreads();
    float tot = red[0] + red[1] + red[2] + red[3];
    float inv = 1.0f / tot;
    float P0 = expm1f(e0 * inv * INV_EPS);
    float P1 = expm1f(e1 * inv * INV_EPS);
    float P2 = expm1f(e2 * inv * INV_EPS);
    float P3 = expm1f(e3 * inv * INV_EPS);
    half4 pv;
    pv[0] = (_Float16)P0; pv[1] = (_Float16)P1;
    pv[2] = (_Float16)P2; pv[3] = (_Float16)P3;
    ((half4*)Pr)[t] = pv;
    float ps = P0 + P1 + P2 + P3;
    __syncthreads();
    for (int o = 32; o; o >>= 1) ps += __shfl_xor(ps, o, 64);
    if (lane == 0) red[w] = ps;
    __syncthreads();
    if (t == 0) {
        float sumP = red[0] + red[1] + red[2] + red[3];
        u[row] = a[row] / ((float)HW + sumP);
    }
}

// K8 (col pass): v_q = b_q / ( sum(u) + sum_p P[p][q] * u_p )
__global__ __launch_bounds__(256) void k_scol(const _Float16* __restrict__ P,
                                              const float* __restrict__ b,
                                              const float* __restrict__ u,
                                              float* __restrict__ v) {
    int n = blockIdx.x, q0 = blockIdx.y * 64;
    __shared__ float us[HW];
    __shared__ float part[4][64];
    __shared__ float xred[4];
    int t = threadIdx.x, lane = t & 63, w = t >> 6;
    float4 u4 = ((const float4*)(u + (size_t)n * HW))[t];
    ((float4*)us)[t] = u4;
    float xs = u4.x + u4.y + u4.z + u4.w;
    for (int o = 32; o; o >>= 1) xs += __shfl_xor(xs, o, 64);
    if (lane == 0) xred[w] = xs;
    __syncthreads();
    float X = xred[0] + xred[1] + xred[2] + xred[3];

    int rsub = lane >> 4, cg = lane & 15;
    const _Float16* Pn = P + (size_t)n * HW * HW + q0 + cg * 4;
    float a0 = 0.f, a1 = 0.f, a2 = 0.f, a3 = 0.f;
    for (int step = 0; step < 64; step++) {
        int p = step * 16 + w * 4 + rsub;
        half4 d4 = *(const half4*)(Pn + (size_t)p * HW);
        float up = us[p];
        a0 = fmaf((float)d4[0], up, a0);
        a1 = fmaf((float)d4[1], up, a1);
        a2 = fmaf((float)d4[2], up, a2);
        a3 = fmaf((float)d4[3], up, a3);
    }
    a0 += __shfl_xor(a0, 16, 64); a0 += __shfl_xor(a0, 32, 64);
    a1 += __shfl_xor(a1, 16, 64); a1 += __shfl_xor(a1, 32, 64);
    a2 += __shfl_xor(a2, 16, 64); a2 += __shfl_xor(a2, 32, 64);
    a3 += __shfl_xor(a3, 16, 64); a3 += __shfl_xor(a3, 32, 64);
    if (rsub == 0) {
        part[w][cg * 4 + 0] = a0;
        part[w][cg * 4 + 1] = a1;
        part[w][cg * 4 + 2] = a2;
        part[w][cg * 4 + 3] = a3;
    }
    __syncthreads();
    if (t < 64) {
        float s = part[0][t] + part[1][t] + part[2][t] + part[3][t];
        v[(size_t)n * HW + q0 + t] = b[(size_t)n * HW + q0 + t] / (X + s);
    }
}

// K9 (row pass): u_p = a_p / ( sum(v) + sum_q P[p][q] * v_q )
__global__ __launch_bounds__(256) void k_srow(const _Float16* __restrict__ P,
                                              const float* __restrict__ marg,
                                              const float* __restrict__ xin,
                                              float* __restrict__ xout) {
    int n = blockIdx.x >> 6;
    int rg = blockIdx.x & 63;          // 16 rows per block
    int t = threadIdx.x, lane = t & 63, w = t >> 6;
    const float* xb = xin + (size_t)n * HW;
    float4 x0 = ((const float4*)xb)[lane * 2];
    float4 x1 = ((const float4*)xb)[lane * 2 + 1];
    float4 x2 = ((const float4*)xb)[128 + lane * 2];
    float4 x3 = ((const float4*)xb)[128 + lane * 2 + 1];
    float xv[16] = {x0.x, x0.y, x0.z, x0.w, x1.x, x1.y, x1.z, x1.w,
                    x2.x, x2.y, x2.z, x2.w, x3.x, x3.y, x3.z, x3.w};
    float X = 0.f;
#pragma unroll
    for (int j = 0; j < 16; j++) X += xv[j];
    for (int o = 32; o; o >>= 1) X += __shfl_xor(X, o, 64);

    for (int r = 0; r < 4; r++) {
        int p = rg * 16 + w * 4 + r;
        const _Float16* Prow = P + ((size_t)n * HW + p) * HW;
        half8 h0 = ((const half8*)Prow)[lane];
        half8 h1 = ((const half8*)Prow)[64 + lane];
        float acc = 0.f;
#pragma unroll
        for (int j = 0; j < 8; j++) acc = fmaf((float)h0[j], xv[j], acc);
#pragma unroll
        for (int j = 0; j < 8; j++) acc = fmaf((float)h1[j], xv[8 + j], acc);
        for (int o = 32; o; o >>= 1) acc += __shfl_xor(acc, o, 64);
        if (lane == 0) {
            xout[(size_t)n * HW + p] = marg[(size_t)n * HW + p] / (X + acc);
        }
    }
}

// K10: fused final col pass + score.
// sD_q = colsum(P*u), sG_q = colsum(G*u) with G = 0.05*log1p(P)*(1+P);
// v2_q = b_q/(sum(u)+sD_q); parts[n*16+qb] = sum_q v2_q * sG_q.
__global__ __launch_bounds__(256) void k_scolfinal(const _Float16* __restrict__ P,
                                                   const float* __restrict__ b,
                                                   const float* __restrict__ u,
                                                   double* __restrict__ parts) {
    int n = blockIdx.x, q0 = blockIdx.y * 64;
    __shared__ float us[HW];
    __shared__ float partD[4][64];
    __shared__ float partG[4][64];
    __shared__ float xred[4];
    int t = threadIdx.x, lane = t & 63, w = t >> 6;
    float4 u4 = ((const float4*)(u + (size_t)n * HW))[t];
    ((float4*)us)[t] = u4;
    float xs = u4.x + u4.y + u4.z + u4.w;
    for (int o = 32; o; o >>= 1) xs += __shfl_xor(xs, o, 64);
    if (lane == 0) xred[w] = xs;
    __syncthreads();
    float X = xred[0] + xred[1] + xred[2] + xred[3];

    int rsub = lane >> 4, cg = lane & 15;
    const _Float16* Pn = P + (size_t)n * HW * HW + q0 + cg * 4;
    float d0 = 0.f, d1 = 0.f, d2 = 0.f, d3 = 0.f;
    float g0 = 0.f, g1 = 0.f, g2 = 0.f, g3 = 0.f;
    for (int step = 0; step < 64; step++) {
        int p = step * 16 + w * 4 + rsub;
        half4 p4 = *(const half4*)(Pn + (size_t)p * HW);
        float up = us[p];
        float P0 = (float)p4[0], P1 = (float)p4[1], P2 = (float)p4[2], P3 = (float)p4[3];
        d0 = fmaf(P0, up, d0); d1 = fmaf(P1, up, d1);
        d2 = fmaf(P2, up, d2); d3 = fmaf(P3, up, d3);
        g0 = fmaf(EPS * log1pf(P0) * (1.f + P0), up, g0);
        g1 = fmaf(EPS * log1pf(P1) * (1.f + P1), up, g1);
        g2 = fmaf(EPS * log1pf(P2) * (1.f + P2), up, g2);
        g3 = fmaf(EPS * log1pf(P3) * (1.f + P3), up, g3);
    }
    d0 += __shfl_xor(d0, 16, 64); d0 += __shfl_xor(d0, 32, 64);
    d1 += __shfl_xor(d1, 16, 64); d1 += __shfl_xor(d1, 32, 64);
    d2 += __shfl_xor(d2, 16, 64); d2 += __shfl_xor(d2, 32, 64);
    d3 += __shfl_xor(d3, 16, 64); d3 += __shfl_xor(d3, 32, 64);
    g0 += __shfl_xor(g0, 16, 64); g0 += __shfl_xor(g0, 32, 64);
    g1 += __shfl_xor(g1, 16, 64); g1 += __shfl_xor(g1, 32, 64);
    g2 += __shfl_xor(g2, 16, 64); g2 += __shfl_xor(g2, 32, 64);
    g3 += __shfl_xor(g3, 16, 64); g3 += __shfl_xor(g3, 32, 64);
    if (rsub == 0) {
        partD[w][cg * 4 + 0] = d0; partD[w][cg * 4 + 1] = d1;
        partD[w][cg * 4 + 2] = d2; partD[w][cg * 4 + 3] = d3;
        partG[w][cg * 4 + 0] = g0; partG[w][cg * 4 + 1] = g1;
        partG[w][cg * 4 + 2] = g2; partG[w][cg * 4 + 3] = g3;
    }
    __syncthreads();
    if (t < 64) {
        float sD = partD[0][t] + partD[1][t] + partD[2][t] + partD[3][t];
        float sG = partG[0][t] + partG[1][t] + partG[2][t] + partG[3][t];
        float v2 = b[(size_t)n * HW + q0 + t] / (X + sD);
        float c = v2 * sG;
        for (int o = 32; o; o >>= 1) c += __shfl_xor(c, o, 64);
        if (t == 0) parts[n * 16 + blockIdx.y] = (double)c;
    }
}

// K11: finalize loss = mean_n(-log(sim_n + 1e-8))
__global__ void k_finalize(const double* __restrict__ parts, float* __restrict__ out) {
    if (threadIdx.x == 0) {
        double tot = 0.0;
        for (int n = 0; n < NB; n++) {
            double s = 0.0;
            for (int j = 0; j < 16; j++) s += parts[n * 16 + j];
            tot += -log(s + 1e-8);
        }
        out[0] = (float)(tot / (double)NB);
    }
}

extern "C" void kernel_launch(void* const* d_in, const int* in_sizes, int n_in,
                              void* d_out, int out_size, void* d_ws, size_t ws_size,
                              hipStream_t stream) {
    const float* pred = (const float*)d_in[0];
    const float* targ = (const float*)d_in[1];
    float* out = (float*)d_out;
    char* wsb = (char*)d_ws;
    const size_t MB = 1024 * 1024;

    // XT [0,16), YT [16,32) fp16 (dead after GEMM); P [32,64); Sh [64,96)
    _Float16* XT = (_Float16*)(wsb);
    _Float16* YT = (_Float16*)(wsb + 16 * MB);
    _Float16* P  = (_Float16*)(wsb + 32 * MB);
    _Float16* Sh = (_Float16*)(wsb + 64 * MB);
    // Aux [160MB, ...)
    float* aux = (float*)(wsb + 160 * MB);
    float* pmu = aux;                     // NB*CH
    float* tmu = pmu + NB * CH;           // NB*CH
    float* ymu = tmu + NB * CH;           // CH
    float* a   = ymu + CH;                // NB*HW
    float* b   = a + NB * HW;
    float* u   = b + NB * HW;
    float* v   = u + NB * HW;
    float* innx = v + NB * HW;
    float* inny = innx + NB * HW;
    double* parts = (double*)(inny + NB * HW);   // 256 doubles
    float* pap = (float*)(parts + 256);          // 4*NB*HW each
    float* pat = pap + 4 * NB * HW;
    float* pnx = pat + 4 * NB * HW;
    float* pny = pnx + 4 * NB * HW;

    k_means<<<NB * CH, 256, 0, stream>>>(pred, targ, pmu, tmu);
    k_ymu<<<1, CH, 0, stream>>>(tmu, ymu);
    k_wn4<<<dim3(4, 4, NB), 256, 0, stream>>>(pred, targ, pmu, tmu, ymu, pap, pat, pnx, pny);
    k_prep<<<NB, 256, 0, stream>>>(pap, pat, pnx, pny, a, b, innx, inny);
    k_maketr<<<dim3(16, 8, NB * 2), 256, 0, stream>>>(pred, targ, ymu, innx, inny, XT, YT);
    k_gemm_mfma<<<dim3(8, 8, NB), 256, 0, stream>>>(XT, YT, Sh);
    k_rowsm<<<NB * HW, 256, 0, stream>>>(Sh, a, P, u);            // emits P and u1
    k_scol<<<dim3(NB, 16), 256, 0, stream>>>(P, b, u, v);         // v1
    k_srow<<<NB * 64, 256, 0, stream>>>(P, a, v, u);              // u2
    k_scolfinal<<<dim3(NB, 16), 256, 0, stream>>>(P, b, u, parts);// v2 + score
    k_finalize<<<1, 64, 0, stream>>>(parts, out);
}

// Round 7
// 137.777 us; speedup vs baseline: 1.4630x; 1.4630x over previous
//
#include <hip/hip_runtime.h>
#include <hip/hip_bf16.h>
#include <math.h>

// Problem constants
#define NB 16
#define CH 512
#define HW 1024          // 32*32
#define INV_EPS 20.0f
#define EPS 0.05f

typedef _Float16 half8 __attribute__((ext_vector_type(8)));
typedef _Float16 half4 __attribute__((ext_vector_type(4)));
typedef float f32x4 __attribute__((ext_vector_type(4)));

static __device__ __forceinline__ void gload16(const void* g, void* l) {
    __builtin_amdgcn_global_load_lds(
        (const __attribute__((address_space(1))) unsigned int*)g,
        (__attribute__((address_space(3))) unsigned int*)l, 16, 0, 0);
}

// ---------------------------------------------------------------------------
// K1: per-(n,c) means of pred and target over HW
__global__ __launch_bounds__(256) void k_means(const float* __restrict__ pred,
                                               const float* __restrict__ targ,
                                               float* __restrict__ pmu,
                                               float* __restrict__ tmu) {
    int bid = blockIdx.x;              // n*CH + c
    int t = threadIdx.x;
    float4 a  = ((const float4*)(pred + (size_t)bid * HW))[t];
    float4 b4 = ((const float4*)(targ + (size_t)bid * HW))[t];
    float sp = a.x + a.y + a.z + a.w;
    float st = b4.x + b4.y + b4.z + b4.w;
    __shared__ float l1[4], l2[4];
    int lane = t & 63, w = t >> 6;
    for (int o = 32; o; o >>= 1) { sp += __shfl_xor(sp, o, 64); st += __shfl_xor(st, o, 64); }
    if (lane == 0) { l1[w] = sp; l2[w] = st; }
    __syncthreads();
    if (t == 0) {
        pmu[bid] = (l1[0] + l1[1] + l1[2] + l1[3]) * (1.0f / HW);
        tmu[bid] = (l2[0] + l2[1] + l2[2] + l2[3]) * (1.0f / HW);
    }
}

// K2: ymu[c] = mean over n of tmu[n][c]
__global__ void k_ymu(const float* __restrict__ tmu, float* __restrict__ ymu) {
    int c = threadIdx.x;   // 512 threads
    float s = 0.f;
    for (int n = 0; n < NB; n++) s += tmu[n * CH + c];
    ymu[c] = s * (1.0f / NB);
}

// K3: fused transpose + center + fp16 write + weight-dot/sqnorm partials.
// XT/YT hold CENTERED UNNORMALIZED fp16; normalization applied in GEMM epilogue.
// grid (16 p-tiles, 4 c-strips of 128, NB*2). Partials in (cs*NB+n)*HW+p layout.
__global__ __launch_bounds__(256) void k_wnt(const float* __restrict__ pred,
                                             const float* __restrict__ targ,
                                             const float* __restrict__ pmu,
                                             const float* __restrict__ tmu,
                                             const float* __restrict__ ymu,
                                             _Float16* __restrict__ XT,
                                             _Float16* __restrict__ YT,
                                             float* __restrict__ pap,
                                             float* __restrict__ pat,
                                             float* __restrict__ pnx,
                                             float* __restrict__ pny) {
    int z = blockIdx.z;
    int n = z >> 1, side = z & 1;
    int p0 = blockIdx.x * 64, c0 = blockIdx.y * 128;
    const float* src = side ? targ : pred;
    const float* coefsrc = side ? pmu : tmu;   // pred·tmu, targ·pmu
    _Float16* O = side ? YT : XT;
    float* wout = side ? pat : pap;
    float* nout = side ? pny : pnx;
    __shared__ float til[128][65];
    __shared__ float coef[128], mu[128];
    int t = threadIdx.x;
    if (t < 128) {
        coef[t] = coefsrc[n * CH + c0 + t];
        mu[t] = ymu[c0 + t];
    }
#pragma unroll
    for (int it = 0; it < 8; it++) {
        int c = it * 16 + (t >> 4), f4 = t & 15;
        float4 vv = *(const float4*)&src[((size_t)(n * CH + c0 + c)) * HW + p0 + f4 * 4];
        *(float4*)&til[c][f4 * 4] = vv;
    }
    __syncthreads();
    int pl = t >> 2, cg = t & 3;
    float ap = 0.f, nx = 0.f;
    half8 h[4];
#pragma unroll
    for (int g = 0; g < 4; g++) {
#pragma unroll
        for (int j = 0; j < 8; j++) {
            int c = g * 32 + cg * 8 + j;   // c mod 32 distinct per cg -> no 4-way bank alias
            float x = til[c][pl];
            ap = fmaf(x, coef[c], ap);
            float d = x - mu[c];
            nx = fmaf(d, d, nx);
            h[g][j] = (_Float16)d;
        }
    }
    size_t off = ((size_t)n * HW + p0 + pl) * CH + c0 + cg * 8;
#pragma unroll
    for (int g = 0; g < 4; g++) *(half8*)(O + off + g * 32) = h[g];
    ap += __shfl_xor(ap, 1, 64); ap += __shfl_xor(ap, 2, 64);
    nx += __shfl_xor(nx, 1, 64); nx += __shfl_xor(nx, 2, 64);
    if (cg == 0) {
        size_t o = ((size_t)(blockIdx.y * NB + n)) * HW + p0 + pl;
        wout[o] = ap;
        nout[o] = nx;
    }
}

// K4: combine partials -> normalized marginals a,b + inverse norms
__global__ __launch_bounds__(256) void k_prep(const float* __restrict__ pap,
                                              const float* __restrict__ pat,
                                              const float* __restrict__ pnx,
                                              const float* __restrict__ pny,
                                              float* __restrict__ a,
                                              float* __restrict__ b,
                                              float* __restrict__ innx,
                                              float* __restrict__ inny) {
    int n = blockIdx.x, t = threadIdx.x;
    float4 ap = {0,0,0,0}, at = {0,0,0,0}, nx = {0,0,0,0}, ny = {0,0,0,0};
    for (int cs = 0; cs < 4; cs++) {
        size_t o = (size_t)(cs * NB + n) * (HW / 4) + t;
        float4 x;
        x = ((const float4*)pap)[o]; ap.x += x.x; ap.y += x.y; ap.z += x.z; ap.w += x.w;
        x = ((const float4*)pat)[o]; at.x += x.x; at.y += x.y; at.z += x.z; at.w += x.w;
        x = ((const float4*)pnx)[o]; nx.x += x.x; nx.y += x.y; nx.z += x.z; nx.w += x.w;
        x = ((const float4*)pny)[o]; ny.x += x.x; ny.y += x.y; ny.z += x.z; ny.w += x.w;
    }
    float4 wp, wt;
    wp.x = fmaxf(ap.x, 0.f) + 1e-4f + 1e-5f; wp.y = fmaxf(ap.y, 0.f) + 1e-4f + 1e-5f;
    wp.z = fmaxf(ap.z, 0.f) + 1e-4f + 1e-5f; wp.w = fmaxf(ap.w, 0.f) + 1e-4f + 1e-5f;
    wt.x = fmaxf(at.x, 0.f) + 1e-4f + 1e-5f; wt.y = fmaxf(at.y, 0.f) + 1e-4f + 1e-5f;
    wt.z = fmaxf(at.z, 0.f) + 1e-4f + 1e-5f; wt.w = fmaxf(at.w, 0.f) + 1e-4f + 1e-5f;
    float sp = wp.x + wp.y + wp.z + wp.w;
    float st = wt.x + wt.y + wt.z + wt.w;
    __shared__ float r1[4], r2[4];
    int lane = t & 63, w = t >> 6;
    for (int o = 32; o; o >>= 1) { sp += __shfl_xor(sp, o, 64); st += __shfl_xor(st, o, 64); }
    if (lane == 0) { r1[w] = sp; r2[w] = st; }
    __syncthreads();
    float scp = (float)HW / (r1[0] + r1[1] + r1[2] + r1[3]);
    float sct = (float)HW / (r2[0] + r2[1] + r2[2] + r2[3]);
    ((float4*)(a + (size_t)n * HW))[t] = make_float4(wp.x * scp, wp.y * scp, wp.z * scp, wp.w * scp);
    ((float4*)(b + (size_t)n * HW))[t] = make_float4(wt.x * sct, wt.y * sct, wt.z * sct, wt.w * sct);
    float4 ix, iy;
    ix.x = 1.f / fmaxf(sqrtf(nx.x), 1e-12f); ix.y = 1.f / fmaxf(sqrtf(nx.y), 1e-12f);
    ix.z = 1.f / fmaxf(sqrtf(nx.z), 1e-12f); ix.w = 1.f / fmaxf(sqrtf(nx.w), 1e-12f);
    iy.x = 1.f / fmaxf(sqrtf(ny.x), 1e-12f); iy.y = 1.f / fmaxf(sqrtf(ny.y), 1e-12f);
    iy.z = 1.f / fmaxf(sqrtf(ny.z), 1e-12f); iy.w = 1.f / fmaxf(sqrtf(ny.w), 1e-12f);
    ((float4*)(innx + (size_t)n * HW))[t] = ix;
    ((float4*)(inny + (size_t)n * HW))[t] = iy;
}

// K5: fp16 MFMA GEMM: S[n][p][q] = (XT[p]·YT[q]) * innx_p * inny_q, output fp16.
__global__ __launch_bounds__(256) void k_gemm_mfma(const _Float16* __restrict__ XT,
                                                   const _Float16* __restrict__ YT,
                                                   const float* __restrict__ innx,
                                                   const float* __restrict__ inny,
                                                   _Float16* __restrict__ S) {
    __shared__ char lds[32768];        // 2 bufs x 2 tiles x 8 KB
    int n = blockIdx.z;
    int p0 = blockIdx.y * 128, q0 = blockIdx.x * 128;
    int t = threadIdx.x, lane = t & 63, wid = t >> 6;
    int wr = wid >> 1, wc = wid & 1;

    const _Float16* bases[2] = {
        XT + (size_t)(n * HW + p0) * CH,
        YT + (size_t)(n * HW + q0) * CH };
    const _Float16* gsrc[4];
    int ldso[4];
#pragma unroll
    for (int r = 0; r < 4; r++) {
        int tile = r >> 1;
        int ci = (r & 1) * 256 + t;        // 16B-chunk index within tile (0..511)
        int row = ci >> 2, sp = ci & 3;    // 4 slots of 16B per 64B row
        int sl = sp ^ ((row >> 1) & 3);    // inverse swizzle on source
        gsrc[r] = bases[tile] + (size_t)row * CH + sl * 8;
        ldso[r] = tile * 8192 + ci * 16;   // linear LDS dest
    }

    int qq = lane >> 4, rA = lane & 15;
    int aoff[4], boff[4];
#pragma unroll
    for (int i = 0; i < 4; i++) {
        int ar = wr * 64 + i * 16 + rA;
        aoff[i] = ar * 64 + ((qq ^ ((ar >> 1) & 3)) * 16);
        int br = wc * 64 + i * 16 + rA;
        boff[i] = br * 64 + ((qq ^ ((br >> 1) & 3)) * 16);
    }

    f32x4 acc[4][4] = {};

#pragma unroll
    for (int r = 0; r < 4; r++) gload16(gsrc[r], &lds[ldso[r]]);
    __syncthreads();

    int cur = 0;
    for (int ks = 0; ks < 16; ks++) {
        if (ks < 15) {
            char* dst = &lds[(cur ^ 1) * 16384];
#pragma unroll
            for (int r = 0; r < 4; r++)
                gload16(gsrc[r] + (ks + 1) * 32, dst + ldso[r]);
        }
        const char* bufb = &lds[cur * 16384];
        half8 av[4], bv[4];
#pragma unroll
        for (int i = 0; i < 4; i++) {
            av[i] = *(const half8*)(bufb + aoff[i]);
            bv[i] = *(const half8*)(bufb + 8192 + boff[i]);
        }
#pragma unroll
        for (int i = 0; i < 4; i++)
#pragma unroll
            for (int j = 0; j < 4; j++)
                acc[i][j] = __builtin_amdgcn_mfma_f32_16x16x32_f16(av[i], bv[j], acc[i][j], 0, 0, 0);
        __syncthreads();
        cur ^= 1;
    }

    int rbase = p0 + wr * 64 + ((lane >> 4) << 2);
    int cbase = q0 + wc * 64 + (lane & 15);
    _Float16* Sn = S + (size_t)n * HW * HW;
    float iy4[4];
#pragma unroll
    for (int j = 0; j < 4; j++) iy4[j] = inny[(size_t)n * HW + cbase + j * 16];
#pragma unroll
    for (int i = 0; i < 4; i++)
#pragma unroll
        for (int r = 0; r < 4; r++) {
            float ixr = innx[(size_t)n * HW + rbase + i * 16 + r];
            _Float16* rowp = Sn + (size_t)(rbase + i * 16 + r) * HW + cbase;
#pragma unroll
            for (int j = 0; j < 4; j++)
                rowp[j * 16] = (_Float16)(acc[i][j][r] * ixr * iy4[j]);
        }
}

// K6: row softmax + P,G emit + first Sinkhorn row half-step.
// s = row-softmax; P = expm1(s/eps); G = s*(1+P); u1 = a/(1024+rowsum P)
__global__ __launch_bounds__(256) void k_rowsm(const _Float16* __restrict__ S,
                                               const float* __restrict__ a,
                                               _Float16* __restrict__ P,
                                               _Float16* __restrict__ G,
                                               float* __restrict__ u) {
    size_t row = blockIdx.x;           // n*HW + p
    const _Float16* Sr = S + row * HW;
    _Float16* Pr = P + row * HW;
    _Float16* Gr = G + row * HW;
    int t = threadIdx.x;
    half4 c4 = ((const half4*)Sr)[t];
    float d0 = 1.f - (float)c4[0], d1 = 1.f - (float)c4[1];
    float d2 = 1.f - (float)c4[2], d3 = 1.f - (float)c4[3];
    float mn = fminf(fminf(d0, d1), fminf(d2, d3));
    __shared__ float red[4];
    int lane = t & 63, w = t >> 6;
    for (int o = 32; o; o >>= 1) mn = fminf(mn, __shfl_xor(mn, o, 64));
    if (lane == 0) red[w] = mn;
    __syncthreads();
    float m = fminf(fminf(red[0], red[1]), fminf(red[2], red[3])) + 1e-5f;
    float e0 = expf((1.f - d0 / m) * 2.f);
    float e1 = expf((1.f - d1 / m) * 2.f);
    float e2 = expf((1.f - d2 / m) * 2.f);
    float e3 = expf((1.f - d3 / m) * 2.f);
    float s = e0 + e1 + e2 + e3;
    __syncthreads();
    for (int o = 32; o; o >>= 1) s += __shfl_xor(s, o, 64);
    if (lane == 0) red[w] = s;
    __syncthreads();
    float tot = red[0] + red[1] + red[2] + red[3];
    float inv = 1.0f / tot;
    float s0 = e0 * inv, s1 = e1 * inv, s2 = e2 * inv, s3 = e3 * inv;
    float P0 = expm1f(s0 * INV_EPS), P1 = expm1f(s1 * INV_EPS);
    float P2 = expm1f(s2 * INV_EPS), P3 = expm1f(s3 * INV_EPS);
    half4 pv, gv;
    pv[0] = (_Float16)P0; pv[1] = (_Float16)P1;
    pv[2] = (_Float16)P2; pv[3] = (_Float16)P3;
    gv[0] = (_Float16)(s0 * (1.f + P0));
    gv[1] = (_Float16)(s1 * (1.f + P1));
    gv[2] = (_Float16)(s2 * (1.f + P2));
    gv[3] = (_Float16)(s3 * (1.f + P3));
    ((half4*)Pr)[t] = pv;
    ((half4*)Gr)[t] = gv;
    float ps = P0 + P1 + P2 + P3;
    __syncthreads();
    for (int o = 32; o; o >>= 1) ps += __shfl_xor(ps, o, 64);
    if (lane == 0) red[w] = ps;
    __syncthreads();
    if (t == 0) {
        float sumP = red[0] + red[1] + red[2] + red[3];
        u[row] = a[row] / ((float)HW + sumP);
    }
}

// K7a: partial colsums of P^T u over a 256-row strip.
// grid (NB, 16 qb, 4 rb): pd[((n*16+qb)*4+rb)*64 + col]
__global__ __launch_bounds__(256) void k_scolpart(const _Float16* __restrict__ P,
                                                  const float* __restrict__ u,
                                                  float* __restrict__ pd) {
    int n = blockIdx.x, qb = blockIdx.y, rb = blockIdx.z;
    int q0 = qb * 64;
    __shared__ float us[256];
    __shared__ float part[4][64];
    int t = threadIdx.x, lane = t & 63, w = t >> 6;
    if (t < 64) ((float4*)us)[t] = ((const float4*)(u + (size_t)n * HW + rb * 256))[t];
    __syncthreads();
    int rsub = lane >> 4, cg = lane & 15;
    const _Float16* Pn = P + (size_t)n * HW * HW + q0 + cg * 4;
    float a0 = 0.f, a1 = 0.f, a2 = 0.f, a3 = 0.f;
    for (int step = 0; step < 16; step++) {
        int lp = step * 16 + w * 4 + rsub;
        half4 d4 = *(const half4*)(Pn + (size_t)(rb * 256 + lp) * HW);
        float up = us[lp];
        a0 = fmaf((float)d4[0], up, a0);
        a1 = fmaf((float)d4[1], up, a1);
        a2 = fmaf((float)d4[2], up, a2);
        a3 = fmaf((float)d4[3], up, a3);
    }
    a0 += __shfl_xor(a0, 16, 64); a0 += __shfl_xor(a0, 32, 64);
    a1 += __shfl_xor(a1, 16, 64); a1 += __shfl_xor(a1, 32, 64);
    a2 += __shfl_xor(a2, 16, 64); a2 += __shfl_xor(a2, 32, 64);
    a3 += __shfl_xor(a3, 16, 64); a3 += __shfl_xor(a3, 32, 64);
    if (rsub == 0) {
        part[w][cg * 4 + 0] = a0; part[w][cg * 4 + 1] = a1;
        part[w][cg * 4 + 2] = a2; part[w][cg * 4 + 3] = a3;
    }
    __syncthreads();
    if (t < 64)
        pd[(((size_t)n * 16 + qb) * 4 + rb) * 64 + t] =
            part[0][t] + part[1][t] + part[2][t] + part[3][t];
}

// K7b: v_q = b_q / ( sum(u) + colsum_q )  (combine 4 row-strip partials)
__global__ __launch_bounds__(256) void k_scolcomb(const float* __restrict__ pd,
                                                  const float* __restrict__ b,
                                                  const float* __restrict__ u,
                                                  float* __restrict__ v) {
    int n = blockIdx.x, t = threadIdx.x;
    __shared__ float xred[4];
    float4 u4 = ((const float4*)(u + (size_t)n * HW))[t];
    float xs = u4.x + u4.y + u4.z + u4.w;
    int lane = t & 63, w = t >> 6;
    for (int o = 32; o; o >>= 1) xs += __shfl_xor(xs, o, 64);
    if (lane == 0) xred[w] = xs;
    __syncthreads();
    float X = xred[0] + xred[1] + xred[2] + xred[3];
    int qb = t >> 4, qi = (t & 15) * 4;
    float4 s = {0, 0, 0, 0};
    for (int rb = 0; rb < 4; rb++) {
        float4 x = *(const float4*)&pd[(((size_t)n * 16 + qb) * 4 + rb) * 64 + qi];
        s.x += x.x; s.y += x.y; s.z += x.z; s.w += x.w;
    }
    float4 b4 = ((const float4*)(b + (size_t)n * HW))[t];
    ((float4*)(v + (size_t)n * HW))[t] =
        make_float4(b4.x / (X + s.x), b4.y / (X + s.y), b4.z / (X + s.z), b4.w / (X + s.w));
}

// K8 (row pass): u_p = a_p / ( sum(v) + sum_q P[p][q] * v_q )
__global__ __launch_bounds__(256) void k_srow(const _Float16* __restrict__ P,
                                              const float* __restrict__ marg,
                                              const float* __restrict__ xin,
                                              float* __restrict__ xout) {
    int n = blockIdx.x >> 6;
    int rg = blockIdx.x & 63;          // 16 rows per block
    int t = threadIdx.x, lane = t & 63, w = t >> 6;
    const float* xb = xin + (size_t)n * HW;
    float4 x0 = ((const float4*)xb)[lane * 2];
    float4 x1 = ((const float4*)xb)[lane * 2 + 1];
    float4 x2 = ((const float4*)xb)[128 + lane * 2];
    float4 x3 = ((const float4*)xb)[128 + lane * 2 + 1];
    float xv[16] = {x0.x, x0.y, x0.z, x0.w, x1.x, x1.y, x1.z, x1.w,
                    x2.x, x2.y, x2.z, x2.w, x3.x, x3.y, x3.z, x3.w};
    float X = 0.f;
#pragma unroll
    for (int j = 0; j < 16; j++) X += xv[j];
    for (int o = 32; o; o >>= 1) X += __shfl_xor(X, o, 64);

    for (int r = 0; r < 4; r++) {
        int p = rg * 16 + w * 4 + r;
        const _Float16* Prow = P + ((size_t)n * HW + p) * HW;
        half8 h0 = ((const half8*)Prow)[lane];
        half8 h1 = ((const half8*)Prow)[64 + lane];
        float acc = 0.f;
#pragma unroll
        for (int j = 0; j < 8; j++) acc = fmaf((float)h0[j], xv[j], acc);
#pragma unroll
        for (int j = 0; j < 8; j++) acc = fmaf((float)h1[j], xv[8 + j], acc);
        for (int o = 32; o; o >>= 1) acc += __shfl_xor(acc, o, 64);
        if (lane == 0) {
            xout[(size_t)n * HW + p] = marg[(size_t)n * HW + p] / (X + acc);
        }
    }
}

// K9a: partial colsums of P^T u AND G^T u over a 256-row strip.
__global__ __launch_bounds__(256) void k_sfinpart(const _Float16* __restrict__ P,
                                                  const _Float16* __restrict__ G,
                                                  const float* __restrict__ u,
                                                  float* __restrict__ pd,
                                                  float* __restrict__ pg) {
    int n = blockIdx.x, qb = blockIdx.y, rb = blockIdx.z;
    int q0 = qb * 64;
    __shared__ float us[256];
    __shared__ float partD[4][64];
    __shared__ float partG[4][64];
    int t = threadIdx.x, lane = t & 63, w = t >> 6;
    if (t < 64) ((float4*)us)[t] = ((const float4*)(u + (size_t)n * HW + rb * 256))[t];
    __syncthreads();
    int rsub = lane >> 4, cg = lane & 15;
    const _Float16* Pn = P + (size_t)n * HW * HW + q0 + cg * 4;
    const _Float16* Gn = G + (size_t)n * HW * HW + q0 + cg * 4;
    float d0 = 0.f, d1 = 0.f, d2 = 0.f, d3 = 0.f;
    float g0 = 0.f, g1 = 0.f, g2 = 0.f, g3 = 0.f;
    for (int step = 0; step < 16; step++) {
        int lp = step * 16 + w * 4 + rsub;
        size_t ro = (size_t)(rb * 256 + lp) * HW;
        half4 p4 = *(const half4*)(Pn + ro);
        half4 q4 = *(const half4*)(Gn + ro);
        float up = us[lp];
        d0 = fmaf((float)p4[0], up, d0); d1 = fmaf((float)p4[1], up, d1);
        d2 = fmaf((float)p4[2], up, d2); d3 = fmaf((float)p4[3], up, d3);
        g0 = fmaf((float)q4[0], up, g0); g1 = fmaf((float)q4[1], up, g1);
        g2 = fmaf((float)q4[2], up, g2); g3 = fmaf((float)q4[3], up, g3);
    }
    d0 += __shfl_xor(d0, 16, 64); d0 += __shfl_xor(d0, 32, 64);
    d1 += __shfl_xor(d1, 16, 64); d1 += __shfl_xor(d1, 32, 64);
    d2 += __shfl_xor(d2, 16, 64); d2 += __shfl_xor(d2, 32, 64);
    d3 += __shfl_xor(d3, 16, 64); d3 += __shfl_xor(d3, 32, 64);
    g0 += __shfl_xor(g0, 16, 64); g0 += __shfl_xor(g0, 32, 64);
    g1 += __shfl_xor(g1, 16, 64); g1 += __shfl_xor(g1, 32, 64);
    g2 += __shfl_xor(g2, 16, 64); g2 += __shfl_xor(g2, 32, 64);
    g3 += __shfl_xor(g3, 16, 64); g3 += __shfl_xor(g3, 32, 64);
    if (rsub == 0) {
        partD[w][cg * 4 + 0] = d0; partD[w][cg * 4 + 1] = d1;
        partD[w][cg * 4 + 2] = d2; partD[w][cg * 4 + 3] = d3;
        partG[w][cg * 4 + 0] = g0; partG[w][cg * 4 + 1] = g1;
        partG[w][cg * 4 + 2] = g2; partG[w][cg * 4 + 3] = g3;
    }
    __syncthreads();
    if (t < 64) {
        size_t o = (((size_t)n * 16 + qb) * 4 + rb) * 64 + t;
        pd[o] = partD[0][t] + partD[1][t] + partD[2][t] + partD[3][t];
        pg[o] = partG[0][t] + partG[1][t] + partG[2][t] + partG[3][t];
    }
}

// K9b: v2 = b/(X+sD); parts[n] = sum_q v2_q * sG_q
__global__ __launch_bounds__(256) void k_sfincomb(const float* __restrict__ pd,
                                                  const float* __restrict__ pg,
                                                  const float* __restrict__ b,
                                                  const float* __restrict__ u,
                                                  double* __restrict__ parts) {
    int n = blockIdx.x, t = threadIdx.x;
    __shared__ float xred[4];
    __shared__ double wpart[4];
    float4 u4 = ((const float4*)(u + (size_t)n * HW))[t];
    float xs = u4.x + u4.y + u4.z + u4.w;
    int lane = t & 63, w = t >> 6;
    for (int o = 32; o; o >>= 1) xs += __shfl_xor(xs, o, 64);
    if (lane == 0) xred[w] = xs;
    __syncthreads();
    float X = xred[0] + xred[1] + xred[2] + xred[3];
    int qb = t >> 4, qi = (t & 15) * 4;
    float4 sd = {0, 0, 0, 0}, sg = {0, 0, 0, 0};
    for (int rb = 0; rb < 4; rb++) {
        size_t o = (((size_t)n * 16 + qb) * 4 + rb) * 64 + qi;
        float4 x = *(const float4*)&pd[o];
        sd.x += x.x; sd.y += x.y; sd.z += x.z; sd.w += x.w;
        float4 y = *(const float4*)&pg[o];
        sg.x += y.x; sg.y += y.y; sg.z += y.z; sg.w += y.w;
    }
    float4 b4 = ((const float4*)(b + (size_t)n * HW))[t];
    float c = b4.x / (X + sd.x) * sg.x + b4.y / (X + sd.y) * sg.y
            + b4.z / (X + sd.z) * sg.z + b4.w / (X + sd.w) * sg.w;
    for (int o = 32; o; o >>= 1) c += __shfl_xor(c, o, 64);
    if (lane == 0) wpart[w] = (double)c;
    __syncthreads();
    if (t == 0) parts[n] = wpart[0] + wpart[1] + wpart[2] + wpart[3];
}

// K10: finalize loss = mean_n(-log(sim_n + 1e-8))
__global__ void k_finalize(const double* __restrict__ parts, float* __restrict__ out) {
    if (threadIdx.x == 0) {
        double tot = 0.0;
        for (int n = 0; n < NB; n++) tot += -log(parts[n] + 1e-8);
        out[0] = (float)(tot / (double)NB);
    }
}

extern "C" void kernel_launch(void* const* d_in, const int* in_sizes, int n_in,
                              void* d_out, int out_size, void* d_ws, size_t ws_size,
                              hipStream_t stream) {
    const float* pred = (const float*)d_in[0];
    const float* targ = (const float*)d_in[1];
    float* out = (float*)d_out;
    char* wsb = (char*)d_ws;
    const size_t MB = 1024 * 1024;

    _Float16* XT = (_Float16*)(wsb);             // [0,16MB)
    _Float16* YT = (_Float16*)(wsb + 16 * MB);   // [16,32)
    _Float16* P  = (_Float16*)(wsb + 32 * MB);   // [32,64)
    _Float16* Sh = (_Float16*)(wsb + 64 * MB);   // [64,96)
    _Float16* G  = (_Float16*)(wsb + 96 * MB);   // [96,128)
    float* aux = (float*)(wsb + 160 * MB);
    float* pmu = aux;                     // NB*CH
    float* tmu = pmu + NB * CH;           // NB*CH
    float* ymu = tmu + NB * CH;           // CH
    float* a   = ymu + CH;                // NB*HW
    float* b   = a + NB * HW;
    float* u   = b + NB * HW;
    float* v   = u + NB * HW;
    float* innx = v + NB * HW;
    float* inny = innx + NB * HW;
    double* parts = (double*)(inny + NB * HW);   // NB doubles
    float* pap = (float*)(parts + 64);           // 4*NB*HW each
    float* pat = pap + 4 * NB * HW;
    float* pnx = pat + 4 * NB * HW;
    float* pny = pnx + 4 * NB * HW;
    float* pd  = pny + 4 * NB * HW;              // NB*16*4*64
    float* pg  = pd + NB * 16 * 4 * 64;

    k_means<<<NB * CH, 256, 0, stream>>>(pred, targ, pmu, tmu);
    k_ymu<<<1, CH, 0, stream>>>(tmu, ymu);
    k_wnt<<<dim3(16, 4, NB * 2), 256, 0, stream>>>(pred, targ, pmu, tmu, ymu,
                                                   XT, YT, pap, pat, pnx, pny);
    k_prep<<<NB, 256, 0, stream>>>(pap, pat, pnx, pny, a, b, innx, inny);
    k_gemm_mfma<<<dim3(8, 8, NB), 256, 0, stream>>>(XT, YT, innx, inny, Sh);
    k_rowsm<<<NB * HW, 256, 0, stream>>>(Sh, a, P, G, u);           // P, G, u1
    k_scolpart<<<dim3(NB, 16, 4), 256, 0, stream>>>(P, u, pd);
    k_scolcomb<<<NB, 256, 0, stream>>>(pd, b, u, v);                // v1
    k_srow<<<NB * 64, 256, 0, stream>>>(P, a, v, u);                // u2
    k_sfinpart<<<dim3(NB, 16, 4), 256, 0, stream>>>(P, G, u, pd, pg);
    k_sfincomb<<<NB, 256, 0, stream>>>(pd, pg, b, u, parts);        // v2 + score
    k_finalize<<<1, 64, 0, stream>>>(parts, out);
}